// Round 14
// baseline (260.505 us; speedup 1.0000x reference)
//
#include <hip/hip_runtime.h>

#define N_NODES 50000
#define N_EDGES 800000
#define IN_CH   128
#define HID     64
#define SCAN_BLOCKS ((N_NODES + 255) / 256)   // 196
#define NXCD 8
#define NODES_PER_XCD (N_NODES / NXCD)        // 6250
#define NPANEL (N_NODES / 16)                 // 3125 (exact)
#define PSTR   3072                           // 24 kchunks * 128 elems per xcat panel

typedef __attribute__((ext_vector_type(8))) short bf16x8;
typedef __attribute__((ext_vector_type(4))) float f32x4;

// ---------------- bf16 helpers ----------------

__device__ inline float bfraw(unsigned int bits) {
  float f; __builtin_memcpy(&f, &bits, 4); return f;
}
__device__ inline float bf2f(unsigned short u) {
  return bfraw(((unsigned int)u) << 16);
}
__device__ inline unsigned short f2bf(float f) {
  unsigned int x; __builtin_memcpy(&x, &f, 4);
  return (unsigned short)((x + 0x7FFFu + ((x >> 16) & 1u)) >> 16);
}

// ---------------- CSR build (single atomic pass) ----------------

__global__ __launch_bounds__(256) void k_count_slot(const int* __restrict__ dst,
                                                    int* __restrict__ deg,
                                                    int* __restrict__ slot) {
  int e = blockIdx.x * 256 + threadIdx.x;
  if (e < N_EDGES) slot[e] = atomicAdd(&deg[dst[e]], 1);
}

__global__ __launch_bounds__(256) void k_blocksum(const int* __restrict__ deg,
                                                  int* __restrict__ bsum) {
  int t = threadIdx.x, lane = t & 63, wid = t >> 6;
  int i = blockIdx.x * 256 + t;
  int v = (i < N_NODES) ? deg[i] : 0;
#pragma unroll
  for (int d = 32; d > 0; d >>= 1) v += __shfl_down(v, d);
  __shared__ int ws[4];
  if (lane == 0) ws[wid] = v;
  __syncthreads();
  if (t == 0) bsum[blockIdx.x] = ws[0] + ws[1] + ws[2] + ws[3];
}

__global__ __launch_bounds__(256) void k_scanb(const int* __restrict__ bsum,
                                               int* __restrict__ boff,
                                               int* __restrict__ rowstart) {
  int t = threadIdx.x, lane = t & 63, wid = t >> 6;
  int v = (t < SCAN_BLOCKS) ? bsum[t] : 0;
  int orig = v;
#pragma unroll
  for (int d = 1; d < 64; d <<= 1) {
    int u = __shfl_up(v, d);
    if (lane >= d) v += u;
  }
  __shared__ int ws[4];
  if (lane == 63) ws[wid] = v;
  __syncthreads();
  int off = 0;
  for (int j = 0; j < wid; ++j) off += ws[j];
  if (t < SCAN_BLOCKS) boff[t] = v - orig + off;
  if (t == 0) rowstart[N_NODES] = N_EDGES;
}

__global__ __launch_bounds__(256) void k_local(const int* __restrict__ deg,
                                               const int* __restrict__ boff,
                                               int* __restrict__ rowstart) {
  int t = threadIdx.x, lane = t & 63, wid = t >> 6;
  int i = blockIdx.x * 256 + t;
  int orig = (i < N_NODES) ? deg[i] : 0;
  int v = orig;
#pragma unroll
  for (int d = 1; d < 64; d <<= 1) {
    int u = __shfl_up(v, d);
    if (lane >= d) v += u;
  }
  __shared__ int ws[4];
  if (lane == 63) ws[wid] = v;
  __syncthreads();
  int off = boff[blockIdx.x];
  for (int j = 0; j < wid; ++j) off += ws[j];
  if (i < N_NODES) rowstart[i] = v - orig + off;
}

__global__ __launch_bounds__(256) void k_abs(const int* __restrict__ dst,
                                             const int* __restrict__ rowstart,
                                             int* __restrict__ slot) {
  int e = blockIdx.x * 256 + threadIdx.x;
  if (e < N_EDGES) slot[e] = rowstart[dst[e]] + slot[e];
}

__global__ __launch_bounds__(256) void k_place(const int* __restrict__ src,
                                               const int* __restrict__ slot,
                                               const int* __restrict__ rowstart,
                                               int2* __restrict__ csr_pack) {
  int xcd = blockIdx.x & (NXCD - 1);
  int e = (blockIdx.x >> 3) * 256 + threadIdx.x;
  int lo = rowstart[xcd * NODES_PER_XCD];
  int hi = rowstart[(xcd + 1) * NODES_PER_XCD];
  if (e < N_EDGES) {
    int sl = slot[e];
    if (sl >= lo && sl < hi) csr_pack[sl] = make_int2(src[e], e);
  }
}

// ---------------- fp32 -> bf16 hi/lo split, PANEL layout ----------------
// xcat panel layout: [panel = n/16][kchunk][row = n%16][8 elems], PSTR = 24*128.

__global__ __launch_bounds__(256) void conv_x(const float* __restrict__ x,
                                              unsigned short* __restrict__ xch,
                                              unsigned short* __restrict__ xcl) {
  int idx = blockIdx.x * 256 + threadIdx.x;   // < N*16 exactly
  int n = idx >> 4, kc = idx & 15;
  const float* p = x + (size_t)n * 128 + kc * 8;
  float4 a = *(const float4*)p;
  float4 b = *(const float4*)(p + 4);
  float v[8] = {a.x, a.y, a.z, a.w, b.x, b.y, b.z, b.w};
  unsigned short h[8], l[8];
#pragma unroll
  for (int j = 0; j < 8; ++j) {
    h[j] = f2bf(v[j]);
    l[j] = f2bf(v[j] - bf2f(h[j]));
  }
  uint4 uh = make_uint4((unsigned)h[0] | ((unsigned)h[1] << 16),
                        (unsigned)h[2] | ((unsigned)h[3] << 16),
                        (unsigned)h[4] | ((unsigned)h[5] << 16),
                        (unsigned)h[6] | ((unsigned)h[7] << 16));
  uint4 ul = make_uint4((unsigned)l[0] | ((unsigned)l[1] << 16),
                        (unsigned)l[2] | ((unsigned)l[3] << 16),
                        (unsigned)l[4] | ((unsigned)l[5] << 16),
                        (unsigned)l[6] | ((unsigned)l[7] << 16));
  size_t o = (size_t)(n >> 4) * PSTR + kc * 128 + (n & 15) * 8;
  *(uint4*)&xch[o] = uh;
  *(uint4*)&xcl[o] = ul;
}

// B panel layout: [colpanel = r/16][kchunk][r%16][8], stride K*16 per colpanel.
__global__ __launch_bounds__(256) void convW(const float* __restrict__ Wa,
                                             const float* __restrict__ Wb, int ldW, int K,
                                             unsigned short* __restrict__ Bh,
                                             unsigned short* __restrict__ Bl) {
  int r = blockIdx.x;       // 0..127 (col)
  int k = threadIdx.x;      // 0..K-1 (blockDim == K)
  const float* wsrc = (r < 64) ? (Wa + (size_t)r * ldW) : (Wb + (size_t)(r - 64) * ldW);
  float v = wsrc[k];
  unsigned short hi = f2bf(v);
  size_t o = (size_t)(r >> 4) * ((size_t)K * 16) + (k >> 3) * 128 + (r & 15) * 8 + (k & 7);
  Bh[o] = hi;
  Bl[o] = f2bf(v - bf2f(hi));
}

// ---------------- MFMA dual GEMM (panel operands: 1KB contiguous per load) ----------------

template<int K>
__global__ __launch_bounds__(256)
void gemm_mfma(const unsigned short* __restrict__ Ah, const unsigned short* __restrict__ Al,
               const unsigned short* __restrict__ Bh, const unsigned short* __restrict__ Bl,
               const float* __restrict__ bias,
               unsigned short* __restrict__ outA, float* __restrict__ outB) {
  int t = threadIdx.x;
  int lane = t & 63, wave = t >> 6;
  int r0 = blockIdx.x * 64;
  int col0 = wave * 32;
  int lrow = lane & 15;

  f32x4 z = {0.f, 0.f, 0.f, 0.f};
  f32x4 acc[4][2];
#pragma unroll
  for (int rt = 0; rt < 4; ++rt)
#pragma unroll
    for (int ct = 0; ct < 2; ++ct) acc[rt][ct] = z;

  size_t abase[4];
#pragma unroll
  for (int rt = 0; rt < 4; ++rt) {
    int p = blockIdx.x * 4 + rt;
    if (p > NPANEL - 1) p = NPANEL - 1;
    abase[rt] = (size_t)p * PSTR + (size_t)lane * 8;
  }
  size_t bbase[2];
#pragma unroll
  for (int ct = 0; ct < 2; ++ct)
    bbase[ct] = (size_t)(wave * 2 + ct) * ((size_t)K * 16) + (size_t)lane * 8;

  constexpr int NK = K / 32;
#pragma unroll
  for (int ks = 0; ks < NK; ++ks) {
    bf16x8 ah[4], al[4], bh[2], bl[2];
#pragma unroll
    for (int rt = 0; rt < 4; ++rt) {
      size_t o = abase[rt] + ks * 512;
      ah[rt] = *(const bf16x8*)(Ah + o);
      al[rt] = *(const bf16x8*)(Al + o);
    }
#pragma unroll
    for (int ct = 0; ct < 2; ++ct) {
      size_t o = bbase[ct] + ks * 512;
      bh[ct] = *(const bf16x8*)(Bh + o);
      bl[ct] = *(const bf16x8*)(Bl + o);
    }
#pragma unroll
    for (int rt = 0; rt < 4; ++rt)
#pragma unroll
      for (int ct = 0; ct < 2; ++ct) {
        acc[rt][ct] = __builtin_amdgcn_mfma_f32_16x16x32_bf16(ah[rt], bh[ct], acc[rt][ct], 0, 0, 0);
        acc[rt][ct] = __builtin_amdgcn_mfma_f32_16x16x32_bf16(al[rt], bh[ct], acc[rt][ct], 0, 0, 0);
        acc[rt][ct] = __builtin_amdgcn_mfma_f32_16x16x32_bf16(ah[rt], bl[ct], acc[rt][ct], 0, 0, 0);
      }
  }

  int crow = (lane >> 4) * 4;
#pragma unroll
  for (int ct = 0; ct < 2; ++ct) {
    int col = col0 + ct * 16 + lrow;
    bool isA = (col < 64);
    float bv = 0.f;
    if (!isA) bv = bias[col - 64];
#pragma unroll
    for (int rt = 0; rt < 4; ++rt) {
#pragma unroll
      for (int reg = 0; reg < 4; ++reg) {
        int row = r0 + rt * 16 + crow + reg;
        if (row < N_NODES) {
          float v = acc[rt][ct][reg];
          if (isA) outA[(size_t)row * 64 + col] = f2bf(v);
          else     outB[(size_t)row * 64 + (col - 64)] = v + bv;
        }
      }
    }
  }
}

// ---------------- aggregation (one wave per node) ----------------
// 8 lanes per row (uint4 = 16B/lane), 8 rows per load instruction, unroll x2.
// Output written into the xcat PANEL layout at kchunk offset coff_e/128.

__global__ __launch_bounds__(256)
void agg_fuse(const unsigned short* __restrict__ y_nb, const float* __restrict__ y_rt,
              const int* __restrict__ rowstart, const int2* __restrict__ csr_pack,
              unsigned short* __restrict__ oh, unsigned short* __restrict__ ol,
              int coff_e) {
  int w = (blockIdx.x * 256 + threadIdx.x) >> 6;
  int lane = threadIdx.x & 63;
  if (w >= N_NODES) return;
  int beg = rowstart[w], end = rowstart[w + 1];
  int cnt = end - beg;
  int grp = lane >> 3;      // 0..7: row within an octet
  int l8  = lane & 7;       // features 8*l8 .. 8*l8+7
  float s0 = 0.f, s1 = 0.f, s2 = 0.f, s3 = 0.f;
  float s4 = 0.f, s5 = 0.f, s6 = 0.f, s7 = 0.f;

  int i = 0;
  for (; i + 16 <= cnt; i += 16) {
    int na = csr_pack[beg + i + grp].x;
    int nb = csr_pack[beg + i + 8 + grp].x;
    uint4 a = *(const uint4*)&y_nb[(size_t)na * 64 + l8 * 8];
    uint4 b = *(const uint4*)&y_nb[(size_t)nb * 64 + l8 * 8];
    s0 += bfraw(a.x << 16);  s1 += bfraw(a.x & 0xFFFF0000u);
    s2 += bfraw(a.y << 16);  s3 += bfraw(a.y & 0xFFFF0000u);
    s4 += bfraw(a.z << 16);  s5 += bfraw(a.z & 0xFFFF0000u);
    s6 += bfraw(a.w << 16);  s7 += bfraw(a.w & 0xFFFF0000u);
    s0 += bfraw(b.x << 16);  s1 += bfraw(b.x & 0xFFFF0000u);
    s2 += bfraw(b.y << 16);  s3 += bfraw(b.y & 0xFFFF0000u);
    s4 += bfraw(b.z << 16);  s5 += bfraw(b.z & 0xFFFF0000u);
    s6 += bfraw(b.w << 16);  s7 += bfraw(b.w & 0xFFFF0000u);
  }
  for (; i + 8 <= cnt; i += 8) {
    int na = csr_pack[beg + i + grp].x;
    uint4 a = *(const uint4*)&y_nb[(size_t)na * 64 + l8 * 8];
    s0 += bfraw(a.x << 16);  s1 += bfraw(a.x & 0xFFFF0000u);
    s2 += bfraw(a.y << 16);  s3 += bfraw(a.y & 0xFFFF0000u);
    s4 += bfraw(a.z << 16);  s5 += bfraw(a.z & 0xFFFF0000u);
    s6 += bfraw(a.w << 16);  s7 += bfraw(a.w & 0xFFFF0000u);
  }
  int rem = cnt - i;                 // 0..7
  if (grp < rem) {
    int na = csr_pack[beg + i + grp].x;
    uint4 a = *(const uint4*)&y_nb[(size_t)na * 64 + l8 * 8];
    s0 += bfraw(a.x << 16);  s1 += bfraw(a.x & 0xFFFF0000u);
    s2 += bfraw(a.y << 16);  s3 += bfraw(a.y & 0xFFFF0000u);
    s4 += bfraw(a.z << 16);  s5 += bfraw(a.z & 0xFFFF0000u);
    s6 += bfraw(a.w << 16);  s7 += bfraw(a.w & 0xFFFF0000u);
  }

  s0 += __shfl_xor(s0, 8); s0 += __shfl_xor(s0, 16); s0 += __shfl_xor(s0, 32);
  s1 += __shfl_xor(s1, 8); s1 += __shfl_xor(s1, 16); s1 += __shfl_xor(s1, 32);
  s2 += __shfl_xor(s2, 8); s2 += __shfl_xor(s2, 16); s2 += __shfl_xor(s2, 32);
  s3 += __shfl_xor(s3, 8); s3 += __shfl_xor(s3, 16); s3 += __shfl_xor(s3, 32);
  s4 += __shfl_xor(s4, 8); s4 += __shfl_xor(s4, 16); s4 += __shfl_xor(s4, 32);
  s5 += __shfl_xor(s5, 8); s5 += __shfl_xor(s5, 16); s5 += __shfl_xor(s5, 32);
  s6 += __shfl_xor(s6, 8); s6 += __shfl_xor(s6, 16); s6 += __shfl_xor(s6, 32);
  s7 += __shfl_xor(s7, 8); s7 += __shfl_xor(s7, 16); s7 += __shfl_xor(s7, 32);

  if (grp == 0) {
    float inv = 1.0f / fmaxf((float)cnt, 1.0f);
    const float* rt = &y_rt[(size_t)w * 64 + l8 * 8];
    float4 ra = *(const float4*)rt;
    float4 rb = *(const float4*)(rt + 4);
    float h0 = fmaxf(s0 * inv + ra.x, 0.f);
    float h1 = fmaxf(s1 * inv + ra.y, 0.f);
    float h2 = fmaxf(s2 * inv + ra.z, 0.f);
    float h3 = fmaxf(s3 * inv + ra.w, 0.f);
    float h4 = fmaxf(s4 * inv + rb.x, 0.f);
    float h5 = fmaxf(s5 * inv + rb.y, 0.f);
    float h6 = fmaxf(s6 * inv + rb.z, 0.f);
    float h7 = fmaxf(s7 * inv + rb.w, 0.f);
    unsigned short i0 = f2bf(h0), i1 = f2bf(h1), i2 = f2bf(h2), i3 = f2bf(h3);
    unsigned short i4 = f2bf(h4), i5 = f2bf(h5), i6 = f2bf(h6), i7 = f2bf(h7);
    uint4 ph = make_uint4((unsigned)i0 | ((unsigned)i1 << 16),
                          (unsigned)i2 | ((unsigned)i3 << 16),
                          (unsigned)i4 | ((unsigned)i5 << 16),
                          (unsigned)i6 | ((unsigned)i7 << 16));
    unsigned short j0 = f2bf(h0 - bf2f(i0)), j1 = f2bf(h1 - bf2f(i1));
    unsigned short j2 = f2bf(h2 - bf2f(i2)), j3 = f2bf(h3 - bf2f(i3));
    unsigned short j4 = f2bf(h4 - bf2f(i4)), j5 = f2bf(h5 - bf2f(i5));
    unsigned short j6 = f2bf(h6 - bf2f(i6)), j7 = f2bf(h7 - bf2f(i7));
    uint4 pl = make_uint4((unsigned)j0 | ((unsigned)j1 << 16),
                          (unsigned)j2 | ((unsigned)j3 << 16),
                          (unsigned)j4 | ((unsigned)j5 << 16),
                          (unsigned)j6 | ((unsigned)j7 << 16));
    size_t o = (size_t)(w >> 4) * PSTR + coff_e + l8 * 128 + (w & 15) * 8;
    *(uint4*)&oh[o] = ph;
    *(uint4*)&ol[o] = pl;
  }
}

// ---------------- edge MLP, CSR order ----------------
// 8 lanes per edge (uint4 P load), 8 edges in flight per wave.
// Writes tmp[i] in CSR-slot order (contiguous, XCD-local per k_place's ranges)
// instead of out[eid] random scatter; unpermute restores edge order.

__global__ __launch_bounds__(256)
void edge_mlp_csr(const int* __restrict__ rowstart, const int2* __restrict__ csr_pack,
                  const unsigned short* __restrict__ Pb, const float* __restrict__ Qf,
                  const float* __restrict__ wm2, const float* __restrict__ bm2v,
                  float* __restrict__ tmp) {
  int wv = (blockIdx.x * 256 + threadIdx.x) >> 6;
  if (wv >= N_NODES) return;
  int lane = threadIdx.x & 63;
  int grp = lane >> 3, l8 = lane & 7;
  int beg = rowstart[wv], end = rowstart[wv + 1];
  if (beg == end) return;
  const float* qp = &Qf[(size_t)wv * 64 + l8 * 8];
  float4 qa = *(const float4*)qp;
  float4 qb = *(const float4*)(qp + 4);
  float4 wa = *(const float4*)&wm2[l8 * 8];
  float4 wb = *(const float4*)&wm2[l8 * 8 + 4];
  float b2 = bm2v[0];
  for (int i = beg + grp; i < end; i += 8) {
    int s = csr_pack[i].x;
    uint4 pu = *(const uint4*)&Pb[(size_t)s * 64 + l8 * 8];
    float p0 = bfraw(pu.x << 16), p1 = bfraw(pu.x & 0xFFFF0000u);
    float p2 = bfraw(pu.y << 16), p3 = bfraw(pu.y & 0xFFFF0000u);
    float p4 = bfraw(pu.z << 16), p5 = bfraw(pu.z & 0xFFFF0000u);
    float p6 = bfraw(pu.w << 16), p7 = bfraw(pu.w & 0xFFFF0000u);
    float part = fmaxf(p0 + qa.x, 0.f) * wa.x
               + fmaxf(p1 + qa.y, 0.f) * wa.y
               + fmaxf(p2 + qa.z, 0.f) * wa.z
               + fmaxf(p3 + qa.w, 0.f) * wa.w
               + fmaxf(p4 + qb.x, 0.f) * wb.x
               + fmaxf(p5 + qb.y, 0.f) * wb.y
               + fmaxf(p6 + qb.z, 0.f) * wb.z
               + fmaxf(p7 + qb.w, 0.f) * wb.w;
    part += __shfl_xor(part, 1);
    part += __shfl_xor(part, 2);
    part += __shfl_xor(part, 4);
    if (l8 == 0) tmp[i] = part + b2;
  }
}

// ---------------- unpermute: out[e] = tmp[slot[e]] ----------------
// slot read coalesced; tmp is a 3.2 MB L2/L3-resident table (random read);
// out written fully coalesced.

__global__ __launch_bounds__(256)
void unpermute(const float* __restrict__ tmp, const int* __restrict__ slot,
               float* __restrict__ out) {
  int e = blockIdx.x * 256 + threadIdx.x;
  if (e < N_EDGES) out[e] = tmp[slot[e]];
}

// ---------------- launch ----------------

extern "C" void kernel_launch(void* const* d_in, const int* in_sizes, int n_in,
                              void* d_out, int out_size, void* d_ws, size_t ws_size,
                              hipStream_t stream) {
  (void)in_sizes; (void)n_in; (void)out_size; (void)ws_size;
  const float* x   = (const float*)d_in[0];
  const int*   src = (const int*)d_in[1];
  const int*   dst = (const int*)d_in[2];
  const float* Wl0 = (const float*)d_in[3];
  const float* bl0 = (const float*)d_in[4];
  const float* Wr0 = (const float*)d_in[5];
  const float* Wl1 = (const float*)d_in[6];
  const float* bl1 = (const float*)d_in[7];
  const float* Wr1 = (const float*)d_in[8];
  const float* Wl2 = (const float*)d_in[9];
  const float* bl2 = (const float*)d_in[10];
  const float* Wr2 = (const float*)d_in[11];
  const float* Wm1 = (const float*)d_in[12];
  const float* bm1 = (const float*)d_in[13];
  const float* Wm2 = (const float*)d_in[14];
  const float* bm2 = (const float*)d_in[15];
  float* out = (float*)d_out;

  char* ws = (char*)d_ws;
  size_t off = 0;
  auto take = [&](size_t bytes) {
    char* p = ws + off;
    off = (off + bytes + 255) & ~(size_t)255;
    return p;
  };
  int*   deg      = (int*)take((size_t)N_NODES * 4);
  int*   rowstart = (int*)take((size_t)(N_NODES + 1) * 4);
  int*   bsum     = (int*)take((size_t)SCAN_BLOCKS * 4);
  int*   boff     = (int*)take((size_t)SCAN_BLOCKS * 4);
  int*   slot     = (int*)take((size_t)N_EDGES * 4);       // lives until unpermute
  float* tmp      = (float*)take((size_t)N_EDGES * 4);     // CSR-ordered MLP output
  int2*  csr_pack = (int2*)take((size_t)N_EDGES * 8);
  unsigned short* xch = (unsigned short*)take((size_t)NPANEL * PSTR * 2);  // panel hi
  unsigned short* xcl = (unsigned short*)take((size_t)NPANEL * PSTR * 2);  // panel lo
  unsigned short* y_nb = (unsigned short*)take((size_t)N_NODES * 64 * 2);  // also P
  float* y_rt     = (float*)take((size_t)N_NODES * 64 * 4);                 // also Q
  unsigned short* W0h = (unsigned short*)take((size_t)128 * 192 * 2);
  unsigned short* W0l = (unsigned short*)take((size_t)128 * 192 * 2);
  unsigned short* W1h = (unsigned short*)take((size_t)128 * 192 * 2);
  unsigned short* W1l = (unsigned short*)take((size_t)128 * 192 * 2);
  unsigned short* W2h = (unsigned short*)take((size_t)128 * 192 * 2);
  unsigned short* W2l = (unsigned short*)take((size_t)128 * 192 * 2);
  unsigned short* Wmh = (unsigned short*)take((size_t)128 * 192 * 2);
  unsigned short* Wml = (unsigned short*)take((size_t)128 * 192 * 2);

  hipMemsetAsync(deg, 0, (size_t)N_NODES * 4, stream);

  int edge_grid = (N_EDGES + 255) / 256;  // 3125
  k_count_slot<<<edge_grid, 256, 0, stream>>>(dst, deg, slot);
  k_blocksum<<<SCAN_BLOCKS, 256, 0, stream>>>(deg, bsum);
  k_scanb<<<1, 256, 0, stream>>>(bsum, boff, rowstart);
  k_local<<<SCAN_BLOCKS, 256, 0, stream>>>(deg, boff, rowstart);
  k_abs<<<edge_grid, 256, 0, stream>>>(dst, rowstart, slot);
  k_place<<<edge_grid * NXCD, 256, 0, stream>>>(src, slot, rowstart, csr_pack);

  // input + weight hi/lo splits (panel layouts)
  conv_x<<<(N_NODES * 16) / 256, 256, 0, stream>>>(x, xch, xcl);  // 3125 blocks exact
  convW<<<128, 128, 0, stream>>>(Wl0, Wr0, IN_CH, 128, W0h, W0l);
  convW<<<128,  64, 0, stream>>>(Wl1, Wr1, HID,   64, W1h, W1l);
  convW<<<128,  64, 0, stream>>>(Wl2, Wr2, HID,   64, W2h, W2l);
  convW<<<128, 192, 0, stream>>>(Wm1, Wm1 + 192, 384, 192, Wmh, Wml);

  int gemm_grid = (N_NODES + 63) / 64;  // 782
  int node_waves_grid = (N_NODES * 64) / 256;  // 12500
  // layer 0: A = x panels (kchunks 0..15)
  gemm_mfma<128><<<gemm_grid, 256, 0, stream>>>(xch, xcl, W0h, W0l, bl0, y_nb, y_rt);
  agg_fuse<<<node_waves_grid, 256, 0, stream>>>(y_nb, y_rt, rowstart, csr_pack, xch, xcl, 0);
  // layer 1: A = xcat kchunks 0..7 (cols 0..63)
  gemm_mfma<64><<<gemm_grid, 256, 0, stream>>>(xch, xcl, W1h, W1l, bl1, y_nb, y_rt);
  agg_fuse<<<node_waves_grid, 256, 0, stream>>>(y_nb, y_rt, rowstart, csr_pack, xch, xcl, 1024);
  // layer 2: A = xcat kchunks 8..15 (cols 64..127)
  gemm_mfma<64><<<gemm_grid, 256, 0, stream>>>(xch + 1024, xcl + 1024, W2h, W2l, bl2, y_nb, y_rt);
  agg_fuse<<<node_waves_grid, 256, 0, stream>>>(y_nb, y_rt, rowstart, csr_pack, xch, xcl, 2048);
  // P (bf16) | Q + bm1 (fp32): A = xcat kchunks 0..23, K = 192
  gemm_mfma<192><<<gemm_grid, 256, 0, stream>>>(xch, xcl, Wmh, Wml, bm1, y_nb, y_rt);
  edge_mlp_csr<<<node_waves_grid, 256, 0, stream>>>(rowstart, csr_pack, y_nb, y_rt, Wm2, bm2, tmp);
  unpermute<<<edge_grid, 256, 0, stream>>>(tmp, slot, out);
}

// Round 15
// 259.501 us; speedup vs baseline: 1.0039x; 1.0039x over previous
//
#include <hip/hip_runtime.h>

#define N_NODES 50000
#define N_EDGES 800000
#define IN_CH   128
#define HID     64
#define SCAN_BLOCKS ((N_NODES + 255) / 256)   // 196
#define NXCD 8
#define NODES_PER_XCD (N_NODES / NXCD)        // 6250
#define NPANEL (N_NODES / 16)                 // 3125 (exact)
#define PSTR   3072                           // 24 kchunks * 128 elems per xcat panel

typedef __attribute__((ext_vector_type(8))) short bf16x8;
typedef __attribute__((ext_vector_type(4))) float f32x4;

// ---------------- bf16 helpers ----------------

__device__ inline float bfraw(unsigned int bits) {
  float f; __builtin_memcpy(&f, &bits, 4); return f;
}
__device__ inline float bf2f(unsigned short u) {
  return bfraw(((unsigned int)u) << 16);
}
__device__ inline unsigned short f2bf(float f) {
  unsigned int x; __builtin_memcpy(&x, &f, 4);
  return (unsigned short)((x + 0x7FFFu + ((x >> 16) & 1u)) >> 16);
}

// ---------------- CSR build (single atomic pass) ----------------

__global__ __launch_bounds__(256) void k_count_slot(const int* __restrict__ dst,
                                                    int* __restrict__ deg,
                                                    int* __restrict__ slot) {
  int e = blockIdx.x * 256 + threadIdx.x;
  if (e < N_EDGES) slot[e] = atomicAdd(&deg[dst[e]], 1);
}

__global__ __launch_bounds__(256) void k_blocksum(const int* __restrict__ deg,
                                                  int* __restrict__ bsum) {
  int t = threadIdx.x, lane = t & 63, wid = t >> 6;
  int i = blockIdx.x * 256 + t;
  int v = (i < N_NODES) ? deg[i] : 0;
#pragma unroll
  for (int d = 32; d > 0; d >>= 1) v += __shfl_down(v, d);
  __shared__ int ws[4];
  if (lane == 0) ws[wid] = v;
  __syncthreads();
  if (t == 0) bsum[blockIdx.x] = ws[0] + ws[1] + ws[2] + ws[3];
}

__global__ __launch_bounds__(256) void k_scanb(const int* __restrict__ bsum,
                                               int* __restrict__ boff,
                                               int* __restrict__ rowstart) {
  int t = threadIdx.x, lane = t & 63, wid = t >> 6;
  int v = (t < SCAN_BLOCKS) ? bsum[t] : 0;
  int orig = v;
#pragma unroll
  for (int d = 1; d < 64; d <<= 1) {
    int u = __shfl_up(v, d);
    if (lane >= d) v += u;
  }
  __shared__ int ws[4];
  if (lane == 63) ws[wid] = v;
  __syncthreads();
  int off = 0;
  for (int j = 0; j < wid; ++j) off += ws[j];
  if (t < SCAN_BLOCKS) boff[t] = v - orig + off;
  if (t == 0) rowstart[N_NODES] = N_EDGES;
}

__global__ __launch_bounds__(256) void k_local(const int* __restrict__ deg,
                                               const int* __restrict__ boff,
                                               int* __restrict__ rowstart) {
  int t = threadIdx.x, lane = t & 63, wid = t >> 6;
  int i = blockIdx.x * 256 + t;
  int orig = (i < N_NODES) ? deg[i] : 0;
  int v = orig;
#pragma unroll
  for (int d = 1; d < 64; d <<= 1) {
    int u = __shfl_up(v, d);
    if (lane >= d) v += u;
  }
  __shared__ int ws[4];
  if (lane == 63) ws[wid] = v;
  __syncthreads();
  int off = boff[blockIdx.x];
  for (int j = 0; j < wid; ++j) off += ws[j];
  if (i < N_NODES) rowstart[i] = v - orig + off;
}

__global__ __launch_bounds__(256) void k_abs(const int* __restrict__ dst,
                                             const int* __restrict__ rowstart,
                                             int* __restrict__ slot) {
  int e = blockIdx.x * 256 + threadIdx.x;
  if (e < N_EDGES) slot[e] = rowstart[dst[e]] + slot[e];
}

// XCD-partitioned placement; stores ONLY src (eid is never consumed downstream:
// edge_mlp writes tmp[slot-order] and unpermute re-reads via slot[]).
__global__ __launch_bounds__(256) void k_place(const int* __restrict__ src,
                                               const int* __restrict__ slot,
                                               const int* __restrict__ rowstart,
                                               int* __restrict__ csr_src) {
  int xcd = blockIdx.x & (NXCD - 1);
  int e = (blockIdx.x >> 3) * 256 + threadIdx.x;
  int lo = rowstart[xcd * NODES_PER_XCD];
  int hi = rowstart[(xcd + 1) * NODES_PER_XCD];
  if (e < N_EDGES) {
    int sl = slot[e];
    if (sl >= lo && sl < hi) csr_src[sl] = src[e];
  }
}

// ---------------- fp32 -> bf16 hi/lo split, PANEL layout ----------------
// xcat panel layout: [panel = n/16][kchunk][row = n%16][8 elems], PSTR = 24*128.

__global__ __launch_bounds__(256) void conv_x(const float* __restrict__ x,
                                              unsigned short* __restrict__ xch,
                                              unsigned short* __restrict__ xcl) {
  int idx = blockIdx.x * 256 + threadIdx.x;   // < N*16 exactly
  int n = idx >> 4, kc = idx & 15;
  const float* p = x + (size_t)n * 128 + kc * 8;
  float4 a = *(const float4*)p;
  float4 b = *(const float4*)(p + 4);
  float v[8] = {a.x, a.y, a.z, a.w, b.x, b.y, b.z, b.w};
  unsigned short h[8], l[8];
#pragma unroll
  for (int j = 0; j < 8; ++j) {
    h[j] = f2bf(v[j]);
    l[j] = f2bf(v[j] - bf2f(h[j]));
  }
  uint4 uh = make_uint4((unsigned)h[0] | ((unsigned)h[1] << 16),
                        (unsigned)h[2] | ((unsigned)h[3] << 16),
                        (unsigned)h[4] | ((unsigned)h[5] << 16),
                        (unsigned)h[6] | ((unsigned)h[7] << 16));
  uint4 ul = make_uint4((unsigned)l[0] | ((unsigned)l[1] << 16),
                        (unsigned)l[2] | ((unsigned)l[3] << 16),
                        (unsigned)l[4] | ((unsigned)l[5] << 16),
                        (unsigned)l[6] | ((unsigned)l[7] << 16));
  size_t o = (size_t)(n >> 4) * PSTR + kc * 128 + (n & 15) * 8;
  *(uint4*)&xch[o] = uh;
  *(uint4*)&xcl[o] = ul;
}

// B panel layout: [colpanel = r/16][kchunk][r%16][8], stride K*16 per colpanel.
__global__ __launch_bounds__(256) void convW(const float* __restrict__ Wa,
                                             const float* __restrict__ Wb, int ldW, int K,
                                             unsigned short* __restrict__ Bh,
                                             unsigned short* __restrict__ Bl) {
  int r = blockIdx.x;       // 0..127 (col)
  int k = threadIdx.x;      // 0..K-1 (blockDim == K)
  const float* wsrc = (r < 64) ? (Wa + (size_t)r * ldW) : (Wb + (size_t)(r - 64) * ldW);
  float v = wsrc[k];
  unsigned short hi = f2bf(v);
  size_t o = (size_t)(r >> 4) * ((size_t)K * 16) + (k >> 3) * 128 + (r & 15) * 8 + (k & 7);
  Bh[o] = hi;
  Bl[o] = f2bf(v - bf2f(hi));
}

// ---------------- MFMA dual GEMM (panel operands: 1KB contiguous per load) ----------------

template<int K>
__global__ __launch_bounds__(256)
void gemm_mfma(const unsigned short* __restrict__ Ah, const unsigned short* __restrict__ Al,
               const unsigned short* __restrict__ Bh, const unsigned short* __restrict__ Bl,
               const float* __restrict__ bias,
               unsigned short* __restrict__ outA, float* __restrict__ outB) {
  int t = threadIdx.x;
  int lane = t & 63, wave = t >> 6;
  int r0 = blockIdx.x * 64;
  int col0 = wave * 32;
  int lrow = lane & 15;

  f32x4 z = {0.f, 0.f, 0.f, 0.f};
  f32x4 acc[4][2];
#pragma unroll
  for (int rt = 0; rt < 4; ++rt)
#pragma unroll
    for (int ct = 0; ct < 2; ++ct) acc[rt][ct] = z;

  size_t abase[4];
#pragma unroll
  for (int rt = 0; rt < 4; ++rt) {
    int p = blockIdx.x * 4 + rt;
    if (p > NPANEL - 1) p = NPANEL - 1;
    abase[rt] = (size_t)p * PSTR + (size_t)lane * 8;
  }
  size_t bbase[2];
#pragma unroll
  for (int ct = 0; ct < 2; ++ct)
    bbase[ct] = (size_t)(wave * 2 + ct) * ((size_t)K * 16) + (size_t)lane * 8;

  constexpr int NK = K / 32;
#pragma unroll
  for (int ks = 0; ks < NK; ++ks) {
    bf16x8 ah[4], al[4], bh[2], bl[2];
#pragma unroll
    for (int rt = 0; rt < 4; ++rt) {
      size_t o = abase[rt] + ks * 512;
      ah[rt] = *(const bf16x8*)(Ah + o);
      al[rt] = *(const bf16x8*)(Al + o);
    }
#pragma unroll
    for (int ct = 0; ct < 2; ++ct) {
      size_t o = bbase[ct] + ks * 512;
      bh[ct] = *(const bf16x8*)(Bh + o);
      bl[ct] = *(const bf16x8*)(Bl + o);
    }
#pragma unroll
    for (int rt = 0; rt < 4; ++rt)
#pragma unroll
      for (int ct = 0; ct < 2; ++ct) {
        acc[rt][ct] = __builtin_amdgcn_mfma_f32_16x16x32_bf16(ah[rt], bh[ct], acc[rt][ct], 0, 0, 0);
        acc[rt][ct] = __builtin_amdgcn_mfma_f32_16x16x32_bf16(al[rt], bh[ct], acc[rt][ct], 0, 0, 0);
        acc[rt][ct] = __builtin_amdgcn_mfma_f32_16x16x32_bf16(ah[rt], bl[ct], acc[rt][ct], 0, 0, 0);
      }
  }

  int crow = (lane >> 4) * 4;
#pragma unroll
  for (int ct = 0; ct < 2; ++ct) {
    int col = col0 + ct * 16 + lrow;
    bool isA = (col < 64);
    float bv = 0.f;
    if (!isA) bv = bias[col - 64];
#pragma unroll
    for (int rt = 0; rt < 4; ++rt) {
#pragma unroll
      for (int reg = 0; reg < 4; ++reg) {
        int row = r0 + rt * 16 + crow + reg;
        if (row < N_NODES) {
          float v = acc[rt][ct][reg];
          if (isA) outA[(size_t)row * 64 + col] = f2bf(v);
          else     outB[(size_t)row * 64 + (col - 64)] = v + bv;
        }
      }
    }
  }
}

// ---------------- aggregation (one wave per node) ----------------
// 8 lanes per row (uint4 = 16B/lane), 8 rows per load instruction, unroll x2.
// Output written into the xcat PANEL layout at kchunk offset coff_e/128.

__global__ __launch_bounds__(256)
void agg_fuse(const unsigned short* __restrict__ y_nb, const float* __restrict__ y_rt,
              const int* __restrict__ rowstart, const int* __restrict__ csr_src,
              unsigned short* __restrict__ oh, unsigned short* __restrict__ ol,
              int coff_e) {
  int w = (blockIdx.x * 256 + threadIdx.x) >> 6;
  int lane = threadIdx.x & 63;
  if (w >= N_NODES) return;
  int beg = rowstart[w], end = rowstart[w + 1];
  int cnt = end - beg;
  int grp = lane >> 3;      // 0..7: row within an octet
  int l8  = lane & 7;       // features 8*l8 .. 8*l8+7
  float s0 = 0.f, s1 = 0.f, s2 = 0.f, s3 = 0.f;
  float s4 = 0.f, s5 = 0.f, s6 = 0.f, s7 = 0.f;

  int i = 0;
  for (; i + 16 <= cnt; i += 16) {
    int na = csr_src[beg + i + grp];
    int nb = csr_src[beg + i + 8 + grp];
    uint4 a = *(const uint4*)&y_nb[(size_t)na * 64 + l8 * 8];
    uint4 b = *(const uint4*)&y_nb[(size_t)nb * 64 + l8 * 8];
    s0 += bfraw(a.x << 16);  s1 += bfraw(a.x & 0xFFFF0000u);
    s2 += bfraw(a.y << 16);  s3 += bfraw(a.y & 0xFFFF0000u);
    s4 += bfraw(a.z << 16);  s5 += bfraw(a.z & 0xFFFF0000u);
    s6 += bfraw(a.w << 16);  s7 += bfraw(a.w & 0xFFFF0000u);
    s0 += bfraw(b.x << 16);  s1 += bfraw(b.x & 0xFFFF0000u);
    s2 += bfraw(b.y << 16);  s3 += bfraw(b.y & 0xFFFF0000u);
    s4 += bfraw(b.z << 16);  s5 += bfraw(b.z & 0xFFFF0000u);
    s6 += bfraw(b.w << 16);  s7 += bfraw(b.w & 0xFFFF0000u);
  }
  for (; i + 8 <= cnt; i += 8) {
    int na = csr_src[beg + i + grp];
    uint4 a = *(const uint4*)&y_nb[(size_t)na * 64 + l8 * 8];
    s0 += bfraw(a.x << 16);  s1 += bfraw(a.x & 0xFFFF0000u);
    s2 += bfraw(a.y << 16);  s3 += bfraw(a.y & 0xFFFF0000u);
    s4 += bfraw(a.z << 16);  s5 += bfraw(a.z & 0xFFFF0000u);
    s6 += bfraw(a.w << 16);  s7 += bfraw(a.w & 0xFFFF0000u);
  }
  int rem = cnt - i;                 // 0..7
  if (grp < rem) {
    int na = csr_src[beg + i + grp];
    uint4 a = *(const uint4*)&y_nb[(size_t)na * 64 + l8 * 8];
    s0 += bfraw(a.x << 16);  s1 += bfraw(a.x & 0xFFFF0000u);
    s2 += bfraw(a.y << 16);  s3 += bfraw(a.y & 0xFFFF0000u);
    s4 += bfraw(a.z << 16);  s5 += bfraw(a.z & 0xFFFF0000u);
    s6 += bfraw(a.w << 16);  s7 += bfraw(a.w & 0xFFFF0000u);
  }

  s0 += __shfl_xor(s0, 8); s0 += __shfl_xor(s0, 16); s0 += __shfl_xor(s0, 32);
  s1 += __shfl_xor(s1, 8); s1 += __shfl_xor(s1, 16); s1 += __shfl_xor(s1, 32);
  s2 += __shfl_xor(s2, 8); s2 += __shfl_xor(s2, 16); s2 += __shfl_xor(s2, 32);
  s3 += __shfl_xor(s3, 8); s3 += __shfl_xor(s3, 16); s3 += __shfl_xor(s3, 32);
  s4 += __shfl_xor(s4, 8); s4 += __shfl_xor(s4, 16); s4 += __shfl_xor(s4, 32);
  s5 += __shfl_xor(s5, 8); s5 += __shfl_xor(s5, 16); s5 += __shfl_xor(s5, 32);
  s6 += __shfl_xor(s6, 8); s6 += __shfl_xor(s6, 16); s6 += __shfl_xor(s6, 32);
  s7 += __shfl_xor(s7, 8); s7 += __shfl_xor(s7, 16); s7 += __shfl_xor(s7, 32);

  if (grp == 0) {
    float inv = 1.0f / fmaxf((float)cnt, 1.0f);
    const float* rt = &y_rt[(size_t)w * 64 + l8 * 8];
    float4 ra = *(const float4*)rt;
    float4 rb = *(const float4*)(rt + 4);
    float h0 = fmaxf(s0 * inv + ra.x, 0.f);
    float h1 = fmaxf(s1 * inv + ra.y, 0.f);
    float h2 = fmaxf(s2 * inv + ra.z, 0.f);
    float h3 = fmaxf(s3 * inv + ra.w, 0.f);
    float h4 = fmaxf(s4 * inv + rb.x, 0.f);
    float h5 = fmaxf(s5 * inv + rb.y, 0.f);
    float h6 = fmaxf(s6 * inv + rb.z, 0.f);
    float h7 = fmaxf(s7 * inv + rb.w, 0.f);
    unsigned short i0 = f2bf(h0), i1 = f2bf(h1), i2 = f2bf(h2), i3 = f2bf(h3);
    unsigned short i4 = f2bf(h4), i5 = f2bf(h5), i6 = f2bf(h6), i7 = f2bf(h7);
    uint4 ph = make_uint4((unsigned)i0 | ((unsigned)i1 << 16),
                          (unsigned)i2 | ((unsigned)i3 << 16),
                          (unsigned)i4 | ((unsigned)i5 << 16),
                          (unsigned)i6 | ((unsigned)i7 << 16));
    unsigned short j0 = f2bf(h0 - bf2f(i0)), j1 = f2bf(h1 - bf2f(i1));
    unsigned short j2 = f2bf(h2 - bf2f(i2)), j3 = f2bf(h3 - bf2f(i3));
    unsigned short j4 = f2bf(h4 - bf2f(i4)), j5 = f2bf(h5 - bf2f(i5));
    unsigned short j6 = f2bf(h6 - bf2f(i6)), j7 = f2bf(h7 - bf2f(i7));
    uint4 pl = make_uint4((unsigned)j0 | ((unsigned)j1 << 16),
                          (unsigned)j2 | ((unsigned)j3 << 16),
                          (unsigned)j4 | ((unsigned)j5 << 16),
                          (unsigned)j6 | ((unsigned)j7 << 16));
    size_t o = (size_t)(w >> 4) * PSTR + coff_e + l8 * 128 + (w & 15) * 8;
    *(uint4*)&oh[o] = ph;
    *(uint4*)&ol[o] = pl;
  }
}

// ---------------- edge MLP, CSR order ----------------
// 8 lanes per edge (uint4 P load), 8 edges in flight per wave.
// Writes tmp[i] in CSR-slot order; unpermute restores edge order via slot[].

__global__ __launch_bounds__(256)
void edge_mlp_csr(const int* __restrict__ rowstart, const int* __restrict__ csr_src,
                  const unsigned short* __restrict__ Pb, const float* __restrict__ Qf,
                  const float* __restrict__ wm2, const float* __restrict__ bm2v,
                  float* __restrict__ tmp) {
  int wv = (blockIdx.x * 256 + threadIdx.x) >> 6;
  if (wv >= N_NODES) return;
  int lane = threadIdx.x & 63;
  int grp = lane >> 3, l8 = lane & 7;
  int beg = rowstart[wv], end = rowstart[wv + 1];
  if (beg == end) return;
  const float* qp = &Qf[(size_t)wv * 64 + l8 * 8];
  float4 qa = *(const float4*)qp;
  float4 qb = *(const float4*)(qp + 4);
  float4 wa = *(const float4*)&wm2[l8 * 8];
  float4 wb = *(const float4*)&wm2[l8 * 8 + 4];
  float b2 = bm2v[0];
  for (int i = beg + grp; i < end; i += 8) {
    int s = csr_src[i];
    uint4 pu = *(const uint4*)&Pb[(size_t)s * 64 + l8 * 8];
    float p0 = bfraw(pu.x << 16), p1 = bfraw(pu.x & 0xFFFF0000u);
    float p2 = bfraw(pu.y << 16), p3 = bfraw(pu.y & 0xFFFF0000u);
    float p4 = bfraw(pu.z << 16), p5 = bfraw(pu.z & 0xFFFF0000u);
    float p6 = bfraw(pu.w << 16), p7 = bfraw(pu.w & 0xFFFF0000u);
    float part = fmaxf(p0 + qa.x, 0.f) * wa.x
               + fmaxf(p1 + qa.y, 0.f) * wa.y
               + fmaxf(p2 + qa.z, 0.f) * wa.z
               + fmaxf(p3 + qa.w, 0.f) * wa.w
               + fmaxf(p4 + qb.x, 0.f) * wb.x
               + fmaxf(p5 + qb.y, 0.f) * wb.y
               + fmaxf(p6 + qb.z, 0.f) * wb.z
               + fmaxf(p7 + qb.w, 0.f) * wb.w;
    part += __shfl_xor(part, 1);
    part += __shfl_xor(part, 2);
    part += __shfl_xor(part, 4);
    if (l8 == 0) tmp[i] = part + b2;
  }
}

// ---------------- unpermute: out[e] = tmp[slot[e]] ----------------

__global__ __launch_bounds__(256)
void unpermute(const float* __restrict__ tmp, const int* __restrict__ slot,
               float* __restrict__ out) {
  int e = blockIdx.x * 256 + threadIdx.x;
  if (e < N_EDGES) out[e] = tmp[slot[e]];
}

// ---------------- launch ----------------

extern "C" void kernel_launch(void* const* d_in, const int* in_sizes, int n_in,
                              void* d_out, int out_size, void* d_ws, size_t ws_size,
                              hipStream_t stream) {
  (void)in_sizes; (void)n_in; (void)out_size; (void)ws_size;
  const float* x   = (const float*)d_in[0];
  const int*   src = (const int*)d_in[1];
  const int*   dst = (const int*)d_in[2];
  const float* Wl0 = (const float*)d_in[3];
  const float* bl0 = (const float*)d_in[4];
  const float* Wr0 = (const float*)d_in[5];
  const float* Wl1 = (const float*)d_in[6];
  const float* bl1 = (const float*)d_in[7];
  const float* Wr1 = (const float*)d_in[8];
  const float* Wl2 = (const float*)d_in[9];
  const float* bl2 = (const float*)d_in[10];
  const float* Wr2 = (const float*)d_in[11];
  const float* Wm1 = (const float*)d_in[12];
  const float* bm1 = (const float*)d_in[13];
  const float* Wm2 = (const float*)d_in[14];
  const float* bm2 = (const float*)d_in[15];
  float* out = (float*)d_out;

  char* ws = (char*)d_ws;
  size_t off = 0;
  auto take = [&](size_t bytes) {
    char* p = ws + off;
    off = (off + bytes + 255) & ~(size_t)255;
    return p;
  };
  int*   deg      = (int*)take((size_t)N_NODES * 4);
  int*   rowstart = (int*)take((size_t)(N_NODES + 1) * 4);
  int*   bsum     = (int*)take((size_t)SCAN_BLOCKS * 4);
  int*   boff     = (int*)take((size_t)SCAN_BLOCKS * 4);
  int*   slot     = (int*)take((size_t)N_EDGES * 4);       // lives until unpermute
  float* tmp      = (float*)take((size_t)N_EDGES * 4);     // CSR-ordered MLP output
  int*   csr_src  = (int*)take((size_t)N_EDGES * 4);
  unsigned short* xch = (unsigned short*)take((size_t)NPANEL * PSTR * 2);  // panel hi
  unsigned short* xcl = (unsigned short*)take((size_t)NPANEL * PSTR * 2);  // panel lo
  unsigned short* y_nb = (unsigned short*)take((size_t)N_NODES * 64 * 2);  // also P
  float* y_rt     = (float*)take((size_t)N_NODES * 64 * 4);                 // also Q
  unsigned short* W0h = (unsigned short*)take((size_t)128 * 192 * 2);
  unsigned short* W0l = (unsigned short*)take((size_t)128 * 192 * 2);
  unsigned short* W1h = (unsigned short*)take((size_t)128 * 192 * 2);
  unsigned short* W1l = (unsigned short*)take((size_t)128 * 192 * 2);
  unsigned short* W2h = (unsigned short*)take((size_t)128 * 192 * 2);
  unsigned short* W2l = (unsigned short*)take((size_t)128 * 192 * 2);
  unsigned short* Wmh = (unsigned short*)take((size_t)128 * 192 * 2);
  unsigned short* Wml = (unsigned short*)take((size_t)128 * 192 * 2);

  hipMemsetAsync(deg, 0, (size_t)N_NODES * 4, stream);

  int edge_grid = (N_EDGES + 255) / 256;  // 3125
  k_count_slot<<<edge_grid, 256, 0, stream>>>(dst, deg, slot);
  k_blocksum<<<SCAN_BLOCKS, 256, 0, stream>>>(deg, bsum);
  k_scanb<<<1, 256, 0, stream>>>(bsum, boff, rowstart);
  k_local<<<SCAN_BLOCKS, 256, 0, stream>>>(deg, boff, rowstart);
  k_abs<<<edge_grid, 256, 0, stream>>>(dst, rowstart, slot);
  k_place<<<edge_grid * NXCD, 256, 0, stream>>>(src, slot, rowstart, csr_src);

  // input + weight hi/lo splits (panel layouts)
  conv_x<<<(N_NODES * 16) / 256, 256, 0, stream>>>(x, xch, xcl);  // 3125 blocks exact
  convW<<<128, 128, 0, stream>>>(Wl0, Wr0, IN_CH, 128, W0h, W0l);
  convW<<<128,  64, 0, stream>>>(Wl1, Wr1, HID,   64, W1h, W1l);
  convW<<<128,  64, 0, stream>>>(Wl2, Wr2, HID,   64, W2h, W2l);
  convW<<<128, 192, 0, stream>>>(Wm1, Wm1 + 192, 384, 192, Wmh, Wml);

  int gemm_grid = (N_NODES + 63) / 64;  // 782
  int node_waves_grid = (N_NODES * 64) / 256;  // 12500
  // layer 0: A = x panels (kchunks 0..15)
  gemm_mfma<128><<<gemm_grid, 256, 0, stream>>>(xch, xcl, W0h, W0l, bl0, y_nb, y_rt);
  agg_fuse<<<node_waves_grid, 256, 0, stream>>>(y_nb, y_rt, rowstart, csr_src, xch, xcl, 0);
  // layer 1: A = xcat kchunks 0..7 (cols 0..63)
  gemm_mfma<64><<<gemm_grid, 256, 0, stream>>>(xch, xcl, W1h, W1l, bl1, y_nb, y_rt);
  agg_fuse<<<node_waves_grid, 256, 0, stream>>>(y_nb, y_rt, rowstart, csr_src, xch, xcl, 1024);
  // layer 2: A = xcat kchunks 8..15 (cols 64..127)
  gemm_mfma<64><<<gemm_grid, 256, 0, stream>>>(xch + 1024, xcl + 1024, W2h, W2l, bl2, y_nb, y_rt);
  agg_fuse<<<node_waves_grid, 256, 0, stream>>>(y_nb, y_rt, rowstart, csr_src, xch, xcl, 2048);
  // P (bf16) | Q + bm1 (fp32): A = xcat kchunks 0..23, K = 192
  gemm_mfma<192><<<gemm_grid, 256, 0, stream>>>(xch, xcl, Wmh, Wml, bm1, y_nb, y_rt);
  edge_mlp_csr<<<node_waves_grid, 256, 0, stream>>>(rowstart, csr_src, y_nb, y_rt, Wm2, bm2, tmp);
  unpermute<<<edge_grid, 256, 0, stream>>>(tmp, slot, out);
}